// Round 2
// baseline (275.803 us; speedup 1.0000x reference)
//
#include <hip/hip_runtime.h>

#define N_ROWS 8192
#define D_IN 1024
#define D_OUT 4096
#define NGROUPS 8
#define NT_K 16       // K tiles of 64
#define MAX_TILES 40

typedef unsigned short ushort_t;
typedef __attribute__((ext_vector_type(8))) __bf16 bf16x8;
typedef __attribute__((ext_vector_type(4))) float f32x4;

// ctl int-index layout in ws:
//  [0..7] counts  [8..16] offsets  [20..27] cursors  [28] num_tiles
//  [32..191] tiles (int4: g,start,rows,pad) up to 40
//  [512..] sorted row ids (8192)
#define CTL_NT 28
#define CTL_TILES 32
#define CTL_SORTED 512

__device__ __forceinline__ unsigned short f2bf(float f) {
  union { float f; unsigned u; } v; v.f = f;
  unsigned r = v.u + 0x7FFFu + ((v.u >> 16) & 1u);
  return (unsigned short)(r >> 16);
}

__device__ __forceinline__ void gload_lds16(const void* g, void* l) {
  __builtin_amdgcn_global_load_lds(
      (const __attribute__((address_space(1))) void*)g,
      (__attribute__((address_space(3))) void*)l, 16, 0, 0);
}

__global__ void k_zero(int* ctl) {
  if (threadIdx.x < 32) ctl[threadIdx.x] = 0;
}

__global__ void k_count(const int* __restrict__ gi, int* __restrict__ ctl) {
  __shared__ int c[NGROUPS];
  int i = blockIdx.x * 256 + threadIdx.x;
  if (threadIdx.x < NGROUPS) c[threadIdx.x] = 0;
  __syncthreads();
  if (i < N_ROWS) atomicAdd(&c[gi[i]], 1);
  __syncthreads();
  if (threadIdx.x < NGROUPS && c[threadIdx.x] != 0)
    atomicAdd(&ctl[threadIdx.x], c[threadIdx.x]);
}

__global__ void k_prefix(int* ctl) {
  if (threadIdx.x != 0 || blockIdx.x != 0) return;
  int* offs = ctl + 8;
  int* cur = ctl + 20;
  int* tiles = ctl + CTL_TILES;
  int off = 0, T = 0;
  for (int g = 0; g < NGROUPS; ++g) {
    offs[g] = off;
    cur[g] = off;
    int cnt = ctl[g];
    for (int m0 = 0; m0 < cnt; m0 += 256) {
      tiles[T * 4 + 0] = g;
      tiles[T * 4 + 1] = off + m0;
      tiles[T * 4 + 2] = min(256, cnt - m0);
      tiles[T * 4 + 3] = 0;
      ++T;
    }
    off += cnt;
  }
  offs[8] = off;
  ctl[CTL_NT] = T;
}

__global__ void k_scatter(const int* __restrict__ gi, int* __restrict__ ctl,
                          int* __restrict__ sorted) {
  int i = blockIdx.x * 256 + threadIdx.x;
  if (i < N_ROWS) {
    int g = gi[i];
    int pos = atomicAdd(&ctl[20 + g], 1);
    sorted[pos] = i;
  }
}

__global__ void k_convA(const float* __restrict__ A, ushort_t* __restrict__ Ab) {
  size_t i = ((size_t)blockIdx.x * 256 + threadIdx.x) * 4;
  float4 v = *reinterpret_cast<const float4*>(A + i);
  ushort4 o;
  o.x = f2bf(v.x); o.y = f2bf(v.y); o.z = f2bf(v.z); o.w = f2bf(v.w);
  *reinterpret_cast<ushort4*>(Ab + i) = o;
}

// W [g][k][n] f32 -> Wt [g][n][k] bf16
__global__ void k_transW(const float* __restrict__ W, ushort_t* __restrict__ Wt) {
  __shared__ float tile[64][33];
  int g = blockIdx.z;
  int n0 = blockIdx.x * 32;
  int k0 = blockIdx.y * 64;
  int t = threadIdx.x;
  int rn = t & 31, rk = t >> 5;
#pragma unroll
  for (int i = 0; i < 8; ++i) {
    int k = rk + i * 8;
    tile[k][rn] = W[((size_t)g * D_IN + k0 + k) * D_OUT + n0 + rn];
  }
  __syncthreads();
  int wk = t & 63, wnn = t >> 6;
#pragma unroll
  for (int i = 0; i < 8; ++i) {
    int n = wnn + i * 4;
    Wt[((size_t)g * D_OUT + n0 + n) * D_IN + k0 + wk] = f2bf(tile[wk][n]);
  }
}

// ---- 256x256 grouped GEMM, 8 waves (2Mx4N), BK=64, 4-phase/K-tile schedule,
// counted vmcnt (T3+T4) + setprio (T5). LDS [dbuf][k8][row256][8] bf16,
// conflict-free ds_read_b128, linear for global_load_lds.

#define DSR_A(ms)                                                         \
  _Pragma("unroll") for (int ks = 0; ks < 2; ++ks)                        \
      _Pragma("unroll") for (int j = 0; j < 4; ++j)                       \
          Af[ks][j] = *reinterpret_cast<const bf16x8*>(                   \
              AsmF + curo + ks * 8192 + aoff + (ms) * 512 + j * 128);

#define DSR_B(nsel)                                                       \
  _Pragma("unroll") for (int ks = 0; ks < 2; ++ks)                        \
      _Pragma("unroll") for (int j = 0; j < 2; ++j)                       \
          Bf[ks][(nsel) * 2 + j] = *reinterpret_cast<const bf16x8*>(      \
              BsmF + curo + ks * 8192 + boff + (nsel) * 256 + j * 128);

#define MFMA16(ms, ns)                                                    \
  __builtin_amdgcn_s_setprio(1);                                          \
  _Pragma("unroll") for (int ks = 0; ks < 2; ++ks)                        \
      _Pragma("unroll") for (int jm = 0; jm < 4; ++jm)                    \
          _Pragma("unroll") for (int jn = 0; jn < 2; ++jn)                \
              acc[(ms) * 4 + jm][(ns) * 2 + jn] =                         \
                  __builtin_amdgcn_mfma_f32_16x16x32_bf16(                \
                      Af[ks][jm], Bf[ks][(ns) * 2 + jn],                  \
                      acc[(ms) * 4 + jm][(ns) * 2 + jn], 0, 0, 0);        \
  __builtin_amdgcn_s_setprio(0);

#define WAIT_LGK()                                                        \
  asm volatile("s_waitcnt lgkmcnt(0)" ::: "memory");                      \
  __builtin_amdgcn_sched_barrier(0);

#define BAR() asm volatile("s_barrier" ::: "memory");

__global__ __launch_bounds__(512, 2) void k_gemm(
    const ushort_t* __restrict__ Ab, const ushort_t* __restrict__ Wt,
    const int* __restrict__ ctl, const int* __restrict__ sorted,
    const float* __restrict__ bias, float* __restrict__ out) {
  int bid = blockIdx.y * 16 + blockIdx.x;
  int swz = (bid & 7) * 80 + (bid >> 3);   // bijective: 640 % 8 == 0
  int bx = swz & 15, tI = swz >> 4;
  if (tI >= ctl[CTL_NT]) return;
  const int4 tl = reinterpret_cast<const int4*>(ctl + CTL_TILES)[tI];
  const int g = tl.x, start = tl.y, rows = tl.z;
  const int n_base = bx * 256;

  __shared__ ushort_t AsmF[2 * 16384];  // 64 KB
  __shared__ ushort_t BsmF[2 * 16384];  // 64 KB
  __shared__ int rowid[256];

  const int t = threadIdx.x;
  if (t < 256) {
    int idx = start + ((t < rows) ? t : 0);
    rowid[t] = sorted[idx];
  }
  __syncthreads();

  size_t aG[4], bG[4];
  int ldOff[4];
#pragma unroll
  for (int j = 0; j < 4; ++j) {
    int c = j * 512 + t;
    aG[j] = (size_t)rowid[c & 255] * D_IN + (size_t)((c >> 8) * 8);
    bG[j] = ((size_t)(g * D_OUT + n_base + (c & 255))) * D_IN +
            (size_t)((c >> 8) * 8);
    ldOff[j] = (j * 512 + (t & ~63)) * 8;
  }

  const int lane = t & 63;
  const int w = t >> 6;
  const int wm = (w >> 2) * 128;   // 2 wave-rows
  const int wn = (w & 3) * 64;     // 4 wave-cols
  const int fr = lane & 15;
  const int fk = lane >> 4;
  const int aoff = (fk * 256 + wm + fr) * 8;
  const int boff = (fk * 256 + wn + fr) * 8;

  f32x4 acc[8][4];
#pragma unroll
  for (int a = 0; a < 8; ++a)
#pragma unroll
    for (int b = 0; b < 4; ++b) acc[a][b] = (f32x4){0.f, 0.f, 0.f, 0.f};

  // prologue: stage K-tile 0 into buf0 (8 gloads)
#pragma unroll
  for (int j = 0; j < 4; ++j) gload_lds16(Ab + aG[j], AsmF + ldOff[j]);
#pragma unroll
  for (int j = 0; j < 4; ++j) gload_lds16(Wt + bG[j], BsmF + ldOff[j]);

  bf16x8 Af[2][4], Bf[2][4];

  for (int kt = 0; kt < NT_K; ++kt) {
    const int curo = (kt & 1) * 16384;
    const int nxto = 16384 - curo;
    const size_t kn = (size_t)(kt + 1) * 64;
    const bool pf = (kt + 1 < NT_K);

    // issue 2 prefetch loads BEFORE the counted wait so vmcnt never drains to 0
    if (pf) {
      gload_lds16(Ab + aG[0] + kn, AsmF + nxto + ldOff[0]);
      gload_lds16(Ab + aG[1] + kn, AsmF + nxto + ldOff[1]);
      asm volatile("s_waitcnt vmcnt(2)" ::: "memory");  // tile kt's 8 landed
    } else {
      asm volatile("s_waitcnt vmcnt(0)" ::: "memory");
    }
    BAR();

    // phase 0: A mset0 (8 dsr) + B nset0 (4 dsr); MFMA mset0 x nset0
    DSR_A(0);
    DSR_B(0);
    if (pf) {
      gload_lds16(Ab + aG[2] + kn, AsmF + nxto + ldOff[2]);
      gload_lds16(Ab + aG[3] + kn, AsmF + nxto + ldOff[3]);
    }
    BAR();
    WAIT_LGK();
    MFMA16(0, 0);
    BAR();

    // phase 1: B nset1 (4 dsr); MFMA mset0 x nset1
    DSR_B(1);
    if (pf) {
      gload_lds16(Wt + bG[0] + kn, BsmF + nxto + ldOff[0]);
      gload_lds16(Wt + bG[1] + kn, BsmF + nxto + ldOff[1]);
    }
    BAR();
    WAIT_LGK();
    MFMA16(0, 1);
    BAR();

    // phase 2: A mset1 (8 dsr); MFMA mset1 x nset0
    DSR_A(1);
    if (pf) {
      gload_lds16(Wt + bG[2] + kn, BsmF + nxto + ldOff[2]);
      gload_lds16(Wt + bG[3] + kn, BsmF + nxto + ldOff[3]);
    }
    BAR();
    WAIT_LGK();
    MFMA16(1, 0);
    BAR();

    // phase 3: MFMA mset1 x nset1
    MFMA16(1, 1);
    BAR();
  }

  // epilogue: bias + masked scattered row stores
  const float* bp = bias + g * D_OUT + n_base + wn;
  float bv[4];
#pragma unroll
  for (int nb = 0; nb < 4; ++nb) bv[nb] = bp[nb * 16 + fr];
#pragma unroll
  for (int mb = 0; mb < 8; ++mb) {
#pragma unroll
    for (int r = 0; r < 4; ++r) {
      int m = wm + mb * 16 + fk * 4 + r;
      if (m < rows) {
        size_t ro = (size_t)rowid[m] * D_OUT + n_base + wn;
#pragma unroll
        for (int nb = 0; nb < 4; ++nb)
          out[ro + nb * 16 + fr] = acc[mb][nb][r] + bv[nb];
      }
    }
  }
}

// Fallback if workspace is too small: naive fp32 (correct, slow).
__global__ void k_naive(const float* __restrict__ A, const int* __restrict__ gi,
                        const float* __restrict__ W, const float* __restrict__ B,
                        float* __restrict__ out) {
  int row = blockIdx.x;
  int n = blockIdx.y * 256 + threadIdx.x;
  int g = gi[row];
  float s = B[(size_t)g * D_OUT + n];
  const float* wp = W + (size_t)g * D_IN * D_OUT + n;
  const float* a = A + (size_t)row * D_IN;
  for (int k = 0; k < D_IN; ++k) s += a[k] * wp[(size_t)k * D_OUT];
  out[(size_t)row * D_OUT + n] = s;
}

extern "C" void kernel_launch(void* const* d_in, const int* in_sizes, int n_in,
                              void* d_out, int out_size, void* d_ws, size_t ws_size,
                              hipStream_t stream) {
  const float* A = (const float*)d_in[0];
  const int* gi = (const int*)d_in[1];
  const float* W = (const float*)d_in[2];
  const float* B = (const float*)d_in[3];
  float* out = (float*)d_out;

  const size_t A_OFF = 65536;
  const size_t W_OFF = A_OFF + (size_t)N_ROWS * D_IN * 2;
  const size_t NEED = W_OFF + (size_t)NGROUPS * D_IN * D_OUT * 2;

  if (ws_size < NEED) {
    dim3 grid(N_ROWS, D_OUT / 256);
    k_naive<<<grid, dim3(256), 0, stream>>>(A, gi, W, B, out);
    return;
  }

  int* ctl = (int*)d_ws;
  int* sorted = ctl + CTL_SORTED;
  ushort_t* Ab = (ushort_t*)((char*)d_ws + A_OFF);
  ushort_t* Wt = (ushort_t*)((char*)d_ws + W_OFF);

  k_zero<<<1, 32, 0, stream>>>(ctl);
  k_count<<<N_ROWS / 256, 256, 0, stream>>>(gi, ctl);
  k_prefix<<<1, 64, 0, stream>>>(ctl);
  k_scatter<<<N_ROWS / 256, 256, 0, stream>>>(gi, ctl, sorted);
  k_convA<<<(N_ROWS * D_IN / 4) / 256, 256, 0, stream>>>(A, Ab);
  dim3 tg(D_OUT / 32, D_IN / 64, NGROUPS);
  k_transW<<<tg, 256, 0, stream>>>(W, Wt);
  dim3 gg(D_OUT / 256, MAX_TILES);
  k_gemm<<<gg, 512, 0, stream>>>(Ab, Wt, ctl, sorted, B, out);
}

// Round 3
// 207.404 us; speedup vs baseline: 1.3298x; 1.3298x over previous
//
#include <hip/hip_runtime.h>

#define N_ROWS 8192
#define D_IN 1024
#define D_OUT 4096
#define NGROUPS 8
#define NT_K 16       // K tiles of 64
#define MAX_TILES 40

typedef unsigned short ushort_t;
typedef __attribute__((ext_vector_type(8))) __bf16 bf16x8;
typedef __attribute__((ext_vector_type(4))) float f32x4;

// ctl int-index layout in ws:
//  [0..7] counts  [8..16] offsets  [20..27] cursors  [28] num_tiles
//  [32..191] tiles (int4: g,start,rows,pad) up to 40
//  [512..] sorted row ids (8192)
#define CTL_NT 28
#define CTL_TILES 32
#define CTL_SORTED 512

__device__ __forceinline__ unsigned short f2bf(float f) {
  union { float f; unsigned u; } v; v.f = f;
  unsigned r = v.u + 0x7FFFu + ((v.u >> 16) & 1u);
  return (unsigned short)(r >> 16);
}

__device__ __forceinline__ void gload_lds16(const void* g, void* l) {
  __builtin_amdgcn_global_load_lds(
      (const __attribute__((address_space(1))) void*)g,
      (__attribute__((address_space(3))) void*)l, 16, 0, 0);
}

__global__ void k_zero(int* ctl) {
  if (threadIdx.x < 32) ctl[threadIdx.x] = 0;
}

__global__ void k_count(const int* __restrict__ gi, int* __restrict__ ctl) {
  __shared__ int c[NGROUPS];
  int i = blockIdx.x * 256 + threadIdx.x;
  if (threadIdx.x < NGROUPS) c[threadIdx.x] = 0;
  __syncthreads();
  if (i < N_ROWS) atomicAdd(&c[gi[i]], 1);
  __syncthreads();
  if (threadIdx.x < NGROUPS && c[threadIdx.x] != 0)
    atomicAdd(&ctl[threadIdx.x], c[threadIdx.x]);
}

__global__ void k_prefix(int* ctl) {
  if (threadIdx.x != 0 || blockIdx.x != 0) return;
  int* offs = ctl + 8;
  int* cur = ctl + 20;
  int* tiles = ctl + CTL_TILES;
  int off = 0, T = 0;
  for (int g = 0; g < NGROUPS; ++g) {
    offs[g] = off;
    cur[g] = off;
    int cnt = ctl[g];
    for (int m0 = 0; m0 < cnt; m0 += 256) {
      tiles[T * 4 + 0] = g;
      tiles[T * 4 + 1] = off + m0;
      tiles[T * 4 + 2] = min(256, cnt - m0);
      tiles[T * 4 + 3] = 0;
      ++T;
    }
    off += cnt;
  }
  offs[8] = off;
  ctl[CTL_NT] = T;
}

__global__ void k_scatter(const int* __restrict__ gi, int* __restrict__ ctl,
                          int* __restrict__ sorted) {
  int i = blockIdx.x * 256 + threadIdx.x;
  if (i < N_ROWS) {
    int g = gi[i];
    int pos = atomicAdd(&ctl[20 + g], 1);
    sorted[pos] = i;
  }
}

__global__ void k_convA(const float* __restrict__ A, ushort_t* __restrict__ Ab) {
  size_t i = ((size_t)blockIdx.x * 256 + threadIdx.x) * 4;
  float4 v = *reinterpret_cast<const float4*>(A + i);
  ushort4 o;
  o.x = f2bf(v.x); o.y = f2bf(v.y); o.z = f2bf(v.z); o.w = f2bf(v.w);
  *reinterpret_cast<ushort4*>(Ab + i) = o;
}

// W [g][k][n] f32 -> Wt [g][kt16][n4096][k64] bf16, XOR-swizzle baked:
// element (n, k) stored at slot ((k>>3)^(n&7))*8 + (k&7) within the n-row.
__global__ void k_transW(const float* __restrict__ W, ushort_t* __restrict__ Wt) {
  __shared__ float tile[64][33];
  int g = blockIdx.z;
  int n0 = blockIdx.x * 32;
  int k0 = blockIdx.y * 64;
  int kt = k0 >> 6;
  int t = threadIdx.x;
  int rn = t & 31, rk = t >> 5;
#pragma unroll
  for (int i = 0; i < 8; ++i) {
    int k = rk + i * 8;
    tile[k][rn] = W[((size_t)g * D_IN + k0 + k) * D_OUT + n0 + rn];
  }
  __syncthreads();
  int wk = t & 63, wnn = t >> 6;
#pragma unroll
  for (int i = 0; i < 8; ++i) {
    int nl = wnn + i * 4;
    int n = n0 + nl;
    int slot = (wk >> 3) ^ (n & 7);
    Wt[((size_t)(g * 16 + kt) * D_OUT + n) * 64 + slot * 8 + (wk & 7)] =
        f2bf(tile[wk][nl]);
  }
}

// ---- 256x256 grouped GEMM, 8 waves (2Mx4N), BK=64, 4 phases/K-tile,
// LDS [dbuf][row256][k64] 128B rows, XOR-swizzled chunks (T2),
// coalesced 128B-granular staging, counted issue-early drain (T3/T4),
// setprio around MFMA (T5).

#define DSR_A(ms)                                                          \
  _Pragma("unroll") for (int ks = 0; ks < 2; ++ks)                         \
      _Pragma("unroll") for (int jm = 0; jm < 4; ++jm)                     \
          Af[ks][jm] = *reinterpret_cast<const bf16x8*>(                   \
              aCh + cur * 32768 + ((ms) * 64 + jm * 16) * 128 +            \
              ((ks * 64 + fk16) ^ xr));

#define DSR_B(nsel)                                                        \
  _Pragma("unroll") for (int ks = 0; ks < 2; ++ks)                         \
      _Pragma("unroll") for (int jn = 0; jn < 2; ++jn)                     \
          Bf[ks][(nsel) * 2 + jn] = *reinterpret_cast<const bf16x8*>(      \
              bCh + cur * 32768 + ((nsel) * 32 + jn * 16) * 128 +          \
              ((ks * 64 + fk16) ^ xr));

#define MFMA16(ms, ns)                                                     \
  __builtin_amdgcn_s_setprio(1);                                           \
  _Pragma("unroll") for (int ks = 0; ks < 2; ++ks)                         \
      _Pragma("unroll") for (int jm = 0; jm < 4; ++jm)                     \
          _Pragma("unroll") for (int jn = 0; jn < 2; ++jn)                 \
              acc[(ms) * 4 + jm][(ns) * 2 + jn] =                          \
                  __builtin_amdgcn_mfma_f32_16x16x32_bf16(                 \
                      Af[ks][jm], Bf[ks][(ns) * 2 + jn],                   \
                      acc[(ms) * 4 + jm][(ns) * 2 + jn], 0, 0, 0);         \
  __builtin_amdgcn_s_setprio(0);

#define WAIT_LGK()                                                         \
  asm volatile("s_waitcnt lgkmcnt(0)" ::: "memory");                       \
  __builtin_amdgcn_sched_barrier(0);

#define BAR() asm volatile("s_barrier" ::: "memory");

__global__ __launch_bounds__(512, 2) void k_gemm(
    const ushort_t* __restrict__ Ab, const ushort_t* __restrict__ Wt,
    const int* __restrict__ ctl, const int* __restrict__ sorted,
    const float* __restrict__ bias, float* __restrict__ out) {
  // balanced bijective XCD swizzle: each XCD sees 2 n-blocks x all 40 tiles
  int bid = blockIdx.y * 16 + blockIdx.x;
  int hi = bid >> 3;                       // 0..79
  int tI = hi % MAX_TILES;
  int bx = (bid & 7) * 2 + hi / MAX_TILES; // 0..15
  if (tI >= ctl[CTL_NT]) return;
  const int4 tl = reinterpret_cast<const int4*>(ctl + CTL_TILES)[tI];
  const int g = tl.x, start = tl.y, rows = tl.z;
  const int n_base = bx * 256;

  __shared__ ushort_t Asm[2][16384];  // 2 x 32 KB, [row256][k64] 128B rows
  __shared__ ushort_t Bsm[2][16384];
  __shared__ int rowid[256];

  const int t = threadIdx.x;
  const int lane = t & 63;
  const int w = t >> 6;
  if (t < 256) rowid[t] = sorted[start + ((t < rows) ? t : 0)];
  __syncthreads();

  // staging: instr I = j*8+w covers rows I*8..I*8+7; lane -> (row I*8+lr, chunk lc^lr)
  const int lr = lane >> 3, lc = lane & 7;
  const int schunk = lc ^ lr;  // pre-swizzled source chunk (A side)
  size_t aSrc[4];
  const ushort_t* bSrc[4];
  int ldOff[4];
  const ushort_t* bRegion =
      Wt + ((size_t)g * 16 * D_OUT + n_base) * 64;  // + kt*262144
#pragma unroll
  for (int j = 0; j < 4; ++j) {
    int I = j * 8 + w;
    aSrc[j] = (size_t)rowid[I * 8 + lr] * D_IN + schunk * 8;  // + kt*64
    bSrc[j] = bRegion + I * 512 + lane * 8;
    ldOff[j] = I * 1024;  // bytes
  }

  const int fr = lane & 15;
  const int fk = lane >> 4;
  const int fk16 = fk * 16;
  const int xr = (fr & 7) << 4;
  const int wm = (w >> 2) * 128;
  const int wn = (w & 3) * 64;
  const char* aCh = (const char*)Asm + (wm + fr) * 128;
  const char* bCh = (const char*)Bsm + (wn + fr) * 128;

  f32x4 acc[8][4];
#pragma unroll
  for (int a = 0; a < 8; ++a)
#pragma unroll
    for (int b = 0; b < 4; ++b) acc[a][b] = (f32x4){0.f, 0.f, 0.f, 0.f};

  // prologue: stage K-tile 0 into buf 0
#pragma unroll
  for (int j = 0; j < 4; ++j)
    gload_lds16(Ab + aSrc[j], (char*)Asm + ldOff[j]);
#pragma unroll
  for (int j = 0; j < 4; ++j)
    gload_lds16(bSrc[j], (char*)Bsm + ldOff[j]);

  bf16x8 Af[2][4], Bf[2][4];

#pragma unroll 2
  for (int kt = 0; kt < NT_K; ++kt) {
    const int cur = kt & 1;
    const int nxt = cur ^ 1;
    const bool pf = (kt + 1 < NT_K);

    asm volatile("s_waitcnt vmcnt(0)" ::: "memory");
    __builtin_amdgcn_sched_barrier(0);
    BAR();

    // P0: read A-mset0 + B-nset0; issue next tile's A staging
    DSR_A(0);
    DSR_B(0);
    if (pf) {
#pragma unroll
      for (int j = 0; j < 4; ++j)
        gload_lds16(Ab + aSrc[j] + (size_t)(kt + 1) * 64,
                    (char*)Asm + nxt * 32768 + ldOff[j]);
    }
    BAR();
    WAIT_LGK();
    MFMA16(0, 0);
    BAR();

    // P1: read B-nset1; issue next tile's B staging
    DSR_B(1);
    if (pf) {
#pragma unroll
      for (int j = 0; j < 4; ++j)
        gload_lds16(bSrc[j] + (size_t)(kt + 1) * 262144,
                    (char*)Bsm + nxt * 32768 + ldOff[j]);
    }
    BAR();
    WAIT_LGK();
    MFMA16(0, 1);
    BAR();

    // P2: read A-mset1
    DSR_A(1);
    BAR();
    WAIT_LGK();
    MFMA16(1, 0);
    BAR();

    // P3
    MFMA16(1, 1);
  }

  // epilogue: bias + masked scattered row stores
  const float* bp = bias + g * D_OUT + n_base + wn;
  float bv[4];
#pragma unroll
  for (int nb = 0; nb < 4; ++nb) bv[nb] = bp[nb * 16 + fr];
#pragma unroll
  for (int mb = 0; mb < 8; ++mb) {
#pragma unroll
    for (int r = 0; r < 4; ++r) {
      int m = wm + mb * 16 + fk * 4 + r;
      if (m < rows) {
        size_t ro = (size_t)rowid[m] * D_OUT + n_base + wn;
#pragma unroll
        for (int nb = 0; nb < 4; ++nb)
          out[ro + nb * 16 + fr] = acc[mb][nb][r] + bv[nb];
      }
    }
  }
}

// Fallback if workspace is too small: naive fp32 (correct, slow).
__global__ void k_naive(const float* __restrict__ A, const int* __restrict__ gi,
                        const float* __restrict__ W, const float* __restrict__ B,
                        float* __restrict__ out) {
  int row = blockIdx.x;
  int n = blockIdx.y * 256 + threadIdx.x;
  int g = gi[row];
  float s = B[(size_t)g * D_OUT + n];
  const float* wp = W + (size_t)g * D_IN * D_OUT + n;
  const float* a = A + (size_t)row * D_IN;
  for (int k = 0; k < D_IN; ++k) s += a[k] * wp[(size_t)k * D_OUT];
  out[(size_t)row * D_OUT + n] = s;
}

extern "C" void kernel_launch(void* const* d_in, const int* in_sizes, int n_in,
                              void* d_out, int out_size, void* d_ws, size_t ws_size,
                              hipStream_t stream) {
  const float* A = (const float*)d_in[0];
  const int* gi = (const int*)d_in[1];
  const float* W = (const float*)d_in[2];
  const float* B = (const float*)d_in[3];
  float* out = (float*)d_out;

  const size_t A_OFF = 65536;
  const size_t W_OFF = A_OFF + (size_t)N_ROWS * D_IN * 2;
  const size_t NEED = W_OFF + (size_t)NGROUPS * D_IN * D_OUT * 2;

  if (ws_size < NEED) {
    dim3 grid(N_ROWS, D_OUT / 256);
    k_naive<<<grid, dim3(256), 0, stream>>>(A, gi, W, B, out);
    return;
  }

  int* ctl = (int*)d_ws;
  int* sorted = ctl + CTL_SORTED;
  ushort_t* Ab = (ushort_t*)((char*)d_ws + A_OFF);
  ushort_t* Wt = (ushort_t*)((char*)d_ws + W_OFF);

  k_zero<<<1, 32, 0, stream>>>(ctl);
  k_count<<<N_ROWS / 256, 256, 0, stream>>>(gi, ctl);
  k_prefix<<<1, 64, 0, stream>>>(ctl);
  k_scatter<<<N_ROWS / 256, 256, 0, stream>>>(gi, ctl, sorted);
  k_convA<<<(N_ROWS * D_IN / 4) / 256, 256, 0, stream>>>(A, Ab);
  dim3 tg(D_OUT / 32, D_IN / 64, NGROUPS);
  k_transW<<<tg, 256, 0, stream>>>(W, Wt);
  dim3 gg(D_OUT / 256, MAX_TILES);
  k_gemm<<<gg, 512, 0, stream>>>(Ab, Wt, ctl, sorted, B, out);
}

// Round 4
// 172.257 us; speedup vs baseline: 1.6011x; 1.2040x over previous
//
#include <hip/hip_runtime.h>

#define N_ROWS 8192
#define D_IN 1024
#define D_OUT 4096
#define NGROUPS 8
#define NT_K 16       // K tiles of 64
#define MAX_TILES 40

typedef unsigned short ushort_t;
typedef __attribute__((ext_vector_type(8))) __bf16 bf16x8;
typedef __attribute__((ext_vector_type(4))) float f32x4;
typedef __attribute__((ext_vector_type(8))) unsigned short us8;

// ctl int-index layout in ws:
//  [28] num_tiles  [32..191] tiles (int4: g,start,rows,pad) up to 40
//  [512..] sorted row ids (8192)
#define CTL_NT 28
#define CTL_TILES 32
#define CTL_SORTED 512

__device__ __forceinline__ unsigned short f2bf(float f) {
  union { float f; unsigned u; } v; v.f = f;
  unsigned r = v.u + 0x7FFFu + ((v.u >> 16) & 1u);
  return (unsigned short)(r >> 16);
}

__device__ __forceinline__ void gload_lds16(const void* g, void* l) {
  __builtin_amdgcn_global_load_lds(
      (const __attribute__((address_space(1))) void*)g,
      (__attribute__((address_space(3))) void*)l, 16, 0, 0);
}

// Fused count + prefix + tile-build + scatter (one block, 1024 threads).
__global__ void k_sort(const int* __restrict__ gi, int* __restrict__ ctl,
                       int* __restrict__ sorted) {
  __shared__ int cnt[NGROUPS];
  __shared__ int cur[NGROUPS];
  int t = threadIdx.x;
  if (t < NGROUPS) cnt[t] = 0;
  __syncthreads();
  int g[8];
#pragma unroll
  for (int i = 0; i < 8; ++i) {
    g[i] = gi[i * 1024 + t];
    atomicAdd(&cnt[g[i]], 1);
  }
  __syncthreads();
  if (t == 0) {
    int off = 0, T = 0;
    int* tiles = ctl + CTL_TILES;
    for (int gg = 0; gg < NGROUPS; ++gg) {
      cur[gg] = off;
      int c = cnt[gg];
      for (int m0 = 0; m0 < c; m0 += 256) {
        tiles[T * 4 + 0] = gg;
        tiles[T * 4 + 1] = off + m0;
        tiles[T * 4 + 2] = min(256, c - m0);
        tiles[T * 4 + 3] = 0;
        ++T;
      }
      off += c;
    }
    ctl[CTL_NT] = T;
  }
  __syncthreads();
#pragma unroll
  for (int i = 0; i < 8; ++i) {
    int pos = atomicAdd(&cur[g[i]], 1);
    sorted[pos] = i * 1024 + t;
  }
}

__global__ void k_convA(const float* __restrict__ A, ushort_t* __restrict__ Ab) {
  size_t i = ((size_t)blockIdx.x * 256 + threadIdx.x) * 8;
  float4 v0 = *reinterpret_cast<const float4*>(A + i);
  float4 v1 = *reinterpret_cast<const float4*>(A + i + 4);
  us8 o;
  o[0] = f2bf(v0.x); o[1] = f2bf(v0.y); o[2] = f2bf(v0.z); o[3] = f2bf(v0.w);
  o[4] = f2bf(v1.x); o[5] = f2bf(v1.y); o[6] = f2bf(v1.z); o[7] = f2bf(v1.w);
  *reinterpret_cast<us8*>(Ab + i) = o;
}

// W [g][k][n] f32 -> Wt [g][kt16][n4096][k64] bf16, XOR-swizzle baked:
// chunk c (8 k-elems) of row n stored at slot (c ^ (n&7)).
// float4 loads, ushort8 stores; 64k x 64n tile per block.
__global__ void k_transW(const float* __restrict__ W, ushort_t* __restrict__ Wt) {
  __shared__ float tile[64][66];
  int g = blockIdx.z;
  int kt = blockIdx.y;
  int n0 = blockIdx.x * 64;
  int k0 = kt * 64;
  int t = threadIdx.x;
  int ln = (t & 15) * 4;
  int lk = t >> 4;
#pragma unroll
  for (int i = 0; i < 4; ++i) {
    int k = i * 16 + lk;
    float4 v = *reinterpret_cast<const float4*>(
        &W[((size_t)g * D_IN + k0 + k) * D_OUT + n0 + ln]);
    tile[k][ln] = v.x; tile[k][ln + 1] = v.y;
    tile[k][ln + 2] = v.z; tile[k][ln + 3] = v.w;
  }
  __syncthreads();
  int n = t & 63;
  int c0 = t >> 6;
#pragma unroll
  for (int i = 0; i < 2; ++i) {
    int c = c0 + i * 4;
    us8 u;
#pragma unroll
    for (int q = 0; q < 8; ++q) u[q] = f2bf(tile[c * 8 + q][n]);
    int slot = c ^ (n & 7);
    *reinterpret_cast<us8*>(
        &Wt[((size_t)(g * 16 + kt) * D_OUT + n0 + n) * 64 + slot * 8]) = u;
  }
}

// ---- 256x256 grouped GEMM, 8 waves (2Mx4N), BK=64, 4 phases/K-tile,
// derived-wait counted vmcnt (T3+T4), setprio (T5), baked XOR swizzle (T2).
// Stage-call -> LDS-row permutation aligns call batches with phase reads:
//   SA0 (A calls 0,1) = rows {0-63,128-191}   (P0: A-mset0)
//   SA1 (A calls 2,3) = rows {64-127,192-255} (P2: A-mset1)
//   SB0 (B calls 0,1) = rows {0-31,64-95,128-159,192-223} (P0: B-nset0)
//   SB1 (B calls 2,3) = rows {32-63,96-127,160-191,224-255} (P1: B-nset1)
// Steady state per tile: P0 issues SA0'+SB0', P1 issues SB1', P2 issues SA1';
// waits: end-P0 vmcnt(6) [SB1 ready], end-P1 vmcnt(6) [SA1 ready],
//        P3 vmcnt(4) [next SA0+SB0 ready]. Never 0 in main loop.

#define DSR_A(ms)                                                          \
  _Pragma("unroll") for (int ks = 0; ks < 2; ++ks)                         \
      _Pragma("unroll") for (int jm = 0; jm < 4; ++jm)                     \
          Af[ks][jm] = *reinterpret_cast<const bf16x8*>(                   \
              aCh + cur * 32768 + ((ms) * 64 + jm * 16) * 128 +            \
              ((ks * 64 + fk16) ^ xr));

#define DSR_B(nsel)                                                        \
  _Pragma("unroll") for (int ks = 0; ks < 2; ++ks)                         \
      _Pragma("unroll") for (int jn = 0; jn < 2; ++jn)                     \
          Bf[ks][(nsel) * 2 + jn] = *reinterpret_cast<const bf16x8*>(      \
              bCh + cur * 32768 + ((nsel) * 32 + jn * 16) * 128 +          \
              ((ks * 64 + fk16) ^ xr));

#define MFMA16(ms, ns)                                                     \
  __builtin_amdgcn_s_setprio(1);                                           \
  _Pragma("unroll") for (int ks = 0; ks < 2; ++ks)                         \
      _Pragma("unroll") for (int jm = 0; jm < 4; ++jm)                     \
          _Pragma("unroll") for (int jn = 0; jn < 2; ++jn)                 \
              acc[(ms) * 4 + jm][(ns) * 2 + jn] =                          \
                  __builtin_amdgcn_mfma_f32_16x16x32_bf16(                 \
                      Af[ks][jm], Bf[ks][(ns) * 2 + jn],                   \
                      acc[(ms) * 4 + jm][(ns) * 2 + jn], 0, 0, 0);         \
  __builtin_amdgcn_s_setprio(0);

#define WAIT_LGK()                                                         \
  asm volatile("s_waitcnt lgkmcnt(0)" ::: "memory");                       \
  __builtin_amdgcn_sched_barrier(0);

#define WAITV(n)                                                           \
  asm volatile("s_waitcnt vmcnt(" #n ")" ::: "memory");                    \
  __builtin_amdgcn_sched_barrier(0);

#define BAR() asm volatile("s_barrier" ::: "memory");

#define STG_A(j, kt1, buf)                                                 \
  gload_lds16(Ab + aSrc[j] + (size_t)(kt1) * 64,                           \
              (char*)Asm + (buf) * 32768 + aDst[j]);
#define STG_B(j, kt1, buf)                                                 \
  gload_lds16(bSrc[j] + (size_t)(kt1) * 262144,                            \
              (char*)Bsm + (buf) * 32768 + bDst[j]);

__global__ __launch_bounds__(512, 2) void k_gemm(
    const ushort_t* __restrict__ Ab, const ushort_t* __restrict__ Wt,
    const int* __restrict__ ctl, const int* __restrict__ sorted,
    const float* __restrict__ bias, float* __restrict__ out) {
  // balanced bijective XCD swizzle: each XCD sees 2 n-blocks x all tiles
  int bid = blockIdx.y * 16 + blockIdx.x;
  int hi = bid >> 3;                        // 0..79
  int tI = hi % MAX_TILES;
  int bx = (bid & 7) * 2 + hi / MAX_TILES;  // 0..15
  if (tI >= ctl[CTL_NT]) return;
  const int4 tl = reinterpret_cast<const int4*>(ctl + CTL_TILES)[tI];
  const int g = tl.x, start = tl.y, rows = tl.z;
  const int n_base = bx * 256;

  __shared__ ushort_t Asm[2][16384];  // [row256][k64], 128B rows
  __shared__ ushort_t Bsm[2][16384];
  __shared__ int rowid[256];

  const int t = threadIdx.x;
  const int lane = t & 63;
  const int w = t >> 6;
  if (t < 256) rowid[t] = sorted[start + ((t < rows) ? t : 0)];
  __syncthreads();

  // staging geometry: call covers 64 LDS rows (8 rows/wave), 128B/row.
  const int lr = lane >> 3, lc = lane & 7;
  const int schunk = lc ^ lr;  // A source pre-swizzle
  size_t aSrc[4];
  const ushort_t* bSrc[4];
  int aDst[4], bDst[4];
  const ushort_t* bRegion = Wt + ((size_t)g * 16 * D_OUT + n_base) * 64;
#pragma unroll
  for (int j = 0; j < 4; ++j) {
    int IA = w + ((j & 1) << 4) + ((j >> 1) << 3);
    int IB = (w & 3) + ((w >> 2) << 3) + ((j & 1) << 4) + ((j >> 1) << 2);
    aSrc[j] = (size_t)rowid[IA * 8 + lr] * D_IN + schunk * 8;
    bSrc[j] = bRegion + IB * 512 + lane * 8;
    aDst[j] = IA * 1024;
    bDst[j] = IB * 1024;
  }

  const int fr = lane & 15;
  const int fk = lane >> 4;
  const int fk16 = fk * 16;
  const int xr = (fr & 7) << 4;
  const int wm = (w >> 2) * 128;
  const int wn = (w & 3) * 64;
  const char* aCh = (const char*)Asm + (wm + fr) * 128;
  const char* bCh = (const char*)Bsm + (wn + fr) * 128;

  f32x4 acc[8][4];
#pragma unroll
  for (int a = 0; a < 8; ++a)
#pragma unroll
    for (int b = 0; b < 4; ++b) acc[a][b] = (f32x4){0.f, 0.f, 0.f, 0.f};

  // prologue: stage tile 0, oldest-first = SA0, SB0, SB1, SA1
  STG_A(0, 0, 0) STG_A(1, 0, 0)
  STG_B(0, 0, 0) STG_B(1, 0, 0)
  STG_B(2, 0, 0) STG_B(3, 0, 0)
  STG_A(2, 0, 0) STG_A(3, 0, 0)
  WAITV(4)
  BAR();

  bf16x8 Af[2][4], Bf[2][4];

  for (int kt = 0; kt < NT_K; ++kt) {
    const int cur = kt & 1;
    const int nxt = cur ^ 1;
    const bool pf = (kt + 1 < NT_K);

    // P0: dsr A-mset0 + B-nset0; issue SA0'+SB0'
    DSR_A(0);
    DSR_B(0);
    if (pf) {
      STG_A(0, kt + 1, nxt) STG_A(1, kt + 1, nxt)
      STG_B(0, kt + 1, nxt) STG_B(1, kt + 1, nxt)
    }
    BAR();
    WAIT_LGK();
    MFMA16(0, 0);
    if (pf) { WAITV(6) } else { WAITV(2) }
    BAR();

    // P1: dsr B-nset1; issue SB1'
    DSR_B(1);
    if (pf) { STG_B(2, kt + 1, nxt) STG_B(3, kt + 1, nxt) }
    BAR();
    WAIT_LGK();
    MFMA16(0, 1);
    if (pf) { WAITV(6) } else { WAITV(0) }
    BAR();

    // P2: dsr A-mset1; issue SA1'
    DSR_A(1);
    if (pf) { STG_A(2, kt + 1, nxt) STG_A(3, kt + 1, nxt) }
    BAR();
    WAIT_LGK();
    MFMA16(1, 0);
    BAR();

    // P3: pure MFMA; counted wait for next tile's SA0+SB0
    MFMA16(1, 1);
    if (pf) { WAITV(4) }
    BAR();
  }

  // epilogue: bias + masked scattered row stores
  const float* bp = bias + g * D_OUT + n_base + wn;
  float bv[4];
#pragma unroll
  for (int nb = 0; nb < 4; ++nb) bv[nb] = bp[nb * 16 + fr];
#pragma unroll
  for (int mb = 0; mb < 8; ++mb) {
#pragma unroll
    for (int r = 0; r < 4; ++r) {
      int m = wm + mb * 16 + fk * 4 + r;
      if (m < rows) {
        size_t ro = (size_t)rowid[m] * D_OUT + n_base + wn;
#pragma unroll
        for (int nb = 0; nb < 4; ++nb)
          out[ro + nb * 16 + fr] = acc[mb][nb][r] + bv[nb];
      }
    }
  }
}

// Fallback if workspace is too small: naive fp32 (correct, slow).
__global__ void k_naive(const float* __restrict__ A, const int* __restrict__ gi,
                        const float* __restrict__ W, const float* __restrict__ B,
                        float* __restrict__ out) {
  int row = blockIdx.x;
  int n = blockIdx.y * 256 + threadIdx.x;
  int g = gi[row];
  float s = B[(size_t)g * D_OUT + n];
  const float* wp = W + (size_t)g * D_IN * D_OUT + n;
  const float* a = A + (size_t)row * D_IN;
  for (int k = 0; k < D_IN; ++k) s += a[k] * wp[(size_t)k * D_OUT];
  out[(size_t)row * D_OUT + n] = s;
}

extern "C" void kernel_launch(void* const* d_in, const int* in_sizes, int n_in,
                              void* d_out, int out_size, void* d_ws, size_t ws_size,
                              hipStream_t stream) {
  const float* A = (const float*)d_in[0];
  const int* gi = (const int*)d_in[1];
  const float* W = (const float*)d_in[2];
  const float* B = (const float*)d_in[3];
  float* out = (float*)d_out;

  const size_t A_OFF = 65536;
  const size_t W_OFF = A_OFF + (size_t)N_ROWS * D_IN * 2;
  const size_t NEED = W_OFF + (size_t)NGROUPS * D_IN * D_OUT * 2;

  if (ws_size < NEED) {
    dim3 grid(N_ROWS, D_OUT / 256);
    k_naive<<<grid, dim3(256), 0, stream>>>(A, gi, W, B, out);
    return;
  }

  int* ctl = (int*)d_ws;
  int* sorted = ctl + CTL_SORTED;
  ushort_t* Ab = (ushort_t*)((char*)d_ws + A_OFF);
  ushort_t* Wt = (ushort_t*)((char*)d_ws + W_OFF);

  k_sort<<<1, 1024, 0, stream>>>(gi, ctl, sorted);
  k_convA<<<(N_ROWS * D_IN / 8) / 256, 256, 0, stream>>>(A, Ab);
  dim3 tg(D_OUT / 64, D_IN / 64, NGROUPS);
  k_transW<<<tg, 256, 0, stream>>>(W, Wt);
  dim3 gg(D_OUT / 256, MAX_TILES);
  k_gemm<<<gg, 512, 0, stream>>>(Ab, Wt, ctl, sorted, B, out);
}